// Round 4
// baseline (6149.471 us; speedup 1.0000x reference)
//
#include <hip/hip_runtime.h>
#include <hip/hip_bf16.h>
#include <math.h>
#include <stdint.h>

using bf16 = __hip_bfloat16;
typedef __attribute__((ext_vector_type(8))) short short8;   // 8 bf16 (MFMA A/B frag)
typedef __attribute__((ext_vector_type(4))) float floatx4;  // MFMA C/D frag (f32)
typedef __attribute__((ext_vector_type(4))) int int4v;      // i8 K=64 frag / i32 acc

typedef const __attribute__((address_space(1))) void* gptr_t;
typedef __attribute__((address_space(3))) void* lptr_t;

__device__ __forceinline__ void load_lds16(const void* g, void* l) {
    __builtin_amdgcn_global_load_lds((gptr_t)(uintptr_t)g, (lptr_t)(uintptr_t)l, 16, 0, 0);
}

// wait until at most N vector-memory ops outstanding. gfx9 vmcnt 6 bits:
// lo[3:0]=bits3:0, hi[5:4]=bits15:14; lgkm/exp left at max (no wait).
#define WAIT_VM(n) __builtin_amdgcn_s_waitcnt(0x0F70 | ((n) & 15) | (((n) >> 4) << 14))

// tanh(x) = 1 - 2/(exp(2x)+1)
__device__ __forceinline__ float fast_tanh(float x) {
    float e = __expf(2.f * x);
    return 1.f - 2.f / (e + 1.f);
}

// ===========================================================================
// Persistent fused ODE kernel, PLAIN launch (no cooperative API — R2/R3
// showed hipLaunchCooperativeKernel is unusable under this harness).
//
// Deadlock-free residency by pigeonhole slack: 256 blocks x 512 thr,
// 64 KB LDS (HW pool 160 KB -> 2 blocks/CU), __launch_bounds__(512,4)
// caps VGPR at 128 (16 waves/CU = 4/SIMD fits). Per-CU capacity = 2 blocks,
// grid = 256 = half of the 512-slot capacity => ALL blocks co-resident
// under ANY placement; no perfect-packing assumption.
//
// Grid barrier: monotone counter + release/acquire threadfences (cg's
// internals, hand-rolled). Spin is BOUNDED (2^21 iters): a broken barrier
// gives a wrong answer + diagnostics, never a hung container.
//
// Phase bodies: R1's verified dbuf cores (BK=64 slabs, XOR-8 swizzle,
// counted WAIT_VM, identical K-summation order => bit-identical numerics).
// Deltas vs R1: 8 waves/block -> wave tile 32x64 (MT=2,NT=4; arow0=wr*32
// keeps x7 swizzle valid, 32 = 0 mod 8); 2 chunks/matrix/thread staging;
// each block runs 2 column-tiles (tt loop). Waves/CU unchanged (8).
// ===========================================================================

__device__ __forceinline__ void grid_bar(unsigned* cnt, unsigned ep) {
    __syncthreads();                      // per-wave s_waitcnt(0): stores done
    if (threadIdx.x == 0) {
        __threadfence();                  // release: L2 writeback (agent scope)
        atomicAdd(cnt, 1u);               // device-scope by default (m20)
        const unsigned tgt = 256u * ep;
        int it = 0;
        while (__hip_atomic_load(cnt, __ATOMIC_RELAXED, __HIP_MEMORY_SCOPE_AGENT) < tgt
               && it < (1 << 21)) {
            __builtin_amdgcn_s_sleep(2);
            ++it;
        }
        __threadfence();                  // acquire: invalidate L1 + XCD L2
    }
    __syncthreads();
}

// L1: x1i = i8(tanh(x0b . W1^T + b1) * 127).  K=512, N=1024. 128x128 tiles.
__device__ __forceinline__ void p1(const bf16* __restrict__ A, const bf16* __restrict__ W,
                                   const float* __restrict__ bias, int8_t* __restrict__ out,
                                   char* smem, int by, int bxp) {
    constexpr int K = 512, N = 1024, MT = 2, NT = 4;
    bf16* lA = (bf16*)smem;                 // 2 bufs x 8192 elems (16 KB each)
    bf16* lB = (bf16*)(smem + 32768);

    const int tid  = threadIdx.x;
    const int lane = tid & 63, w = tid >> 6;
    const int wr = w >> 1, wc = w & 1;
    const int quad = lane >> 4, l16 = lane & 15;
    const int brow  = by * 128;
    const int arow0 = wr * 32 + l16;
    const int brow0 = wc * 64 + l16;
    const int x7 = l16 & 7;

    int rr[2], ss[2], lq[2];
#pragma unroll
    for (int jj = 0; jj < 2; ++jj) {
        const int q = tid + jj * 512;
        rr[jj] = q >> 3; ss[jj] = (q & 7) ^ (rr[jj] & 7); lq[jj] = q * 8;
    }

    for (int tt = 0; tt < 2; ++tt) {
        const int bcol = (bxp * 2 + tt) * 128;
        const bf16* gA[2]; const bf16* gW[2];
#pragma unroll
        for (int jj = 0; jj < 2; ++jj) {
            gA[jj] = A + (size_t)(brow + rr[jj]) * K + ss[jj] * 8;
            gW[jj] = W + (size_t)(bcol + rr[jj]) * K + ss[jj] * 8;
        }

        floatx4 acc[MT][NT];
        const floatx4 zero = {0.f, 0.f, 0.f, 0.f};
#pragma unroll
        for (int mt = 0; mt < MT; ++mt)
#pragma unroll
            for (int nt = 0; nt < NT; ++nt) acc[mt][nt] = zero;

#pragma unroll
        for (int jj = 0; jj < 2; ++jj) load_lds16(gA[jj], lA + lq[jj]);
#pragma unroll
        for (int jj = 0; jj < 2; ++jj) load_lds16(gW[jj], lB + lq[jj]);

        for (int kt = 0; kt < K / 64; ++kt) {
            const int cur = kt & 1;
            if (kt + 1 < K / 64) {
#pragma unroll
                for (int jj = 0; jj < 2; ++jj)
                    load_lds16(gA[jj] + (kt + 1) * 64, lA + (cur ^ 1) * 8192 + lq[jj]);
#pragma unroll
                for (int jj = 0; jj < 2; ++jj)
                    load_lds16(gW[jj] + (kt + 1) * 64, lB + (cur ^ 1) * 8192 + lq[jj]);
                WAIT_VM(4);
            } else {
                WAIT_VM(0);
            }
            __builtin_amdgcn_s_barrier();

#pragma unroll
            for (int kk = 0; kk < 2; ++kk) {
                const int sw = ((kk * 4 + quad) ^ x7) * 8;
                short8 af[MT], bfr[NT];
#pragma unroll
                for (int mt = 0; mt < MT; ++mt)
                    af[mt] = *(const short8*)(lA + cur * 8192 + (arow0 + mt * 16) * 64 + sw);
#pragma unroll
                for (int nt = 0; nt < NT; ++nt)
                    bfr[nt] = *(const short8*)(lB + cur * 8192 + (brow0 + nt * 16) * 64 + sw);
#pragma unroll
                for (int mt = 0; mt < MT; ++mt)
#pragma unroll
                    for (int nt = 0; nt < NT; ++nt)
                        acc[mt][nt] = __builtin_amdgcn_mfma_f32_16x16x32_bf16(
                            af[mt], bfr[nt], acc[mt][nt], 0, 0, 0);
            }
            __builtin_amdgcn_s_barrier();
        }

        const int m0 = brow + wr * 32 + quad * 4;
        const int n0 = bcol + wc * 64 + l16;
#pragma unroll
        for (int mt = 0; mt < MT; ++mt)
#pragma unroll
            for (int nt = 0; nt < NT; ++nt) {
                const int n = n0 + nt * 16;
                const float bb = bias[n];
#pragma unroll
                for (int i = 0; i < 4; ++i) {
                    const int m = m0 + mt * 16 + i;
                    const float t = fast_tanh(acc[mt][nt][i] + bb);
                    out[(size_t)m * N + n] = (int8_t)__float2int_rn(t * 127.f);
                }
            }
    }
}

// L2: x2b = bf16(tanh(acc*dq[n] + b2)), i8 core. K=1024, N=1024. 128x128.
__device__ __forceinline__ void p2(const int8_t* __restrict__ A, const int8_t* __restrict__ W,
                                   const float* __restrict__ dq, const float* __restrict__ bias,
                                   bf16* __restrict__ out, char* smem, int by, int bxp) {
    constexpr int K = 1024, N = 1024, MT = 2, NT = 4;
    int8_t* lA = (int8_t*)smem;               // 2 bufs x 16 KB
    int8_t* lB = (int8_t*)(smem + 32768);

    const int tid  = threadIdx.x;
    const int lane = tid & 63, w = tid >> 6;
    const int wr = w >> 1, wc = w & 1;
    const int quad = lane >> 4, l16 = lane & 15;
    const int brow  = by * 128;
    const int arow0 = wr * 32 + l16;
    const int brow0 = wc * 64 + l16;
    const int x7 = l16 & 7;

    int rr[2], ss[2], lq[2];
#pragma unroll
    for (int jj = 0; jj < 2; ++jj) {
        const int q = tid + jj * 512;
        rr[jj] = q >> 3; ss[jj] = (q & 7) ^ (rr[jj] & 7); lq[jj] = q * 16;
    }

    for (int tt = 0; tt < 2; ++tt) {
        const int bcol = (bxp * 2 + tt) * 128;
        const int8_t* gA[2]; const int8_t* gW[2];
#pragma unroll
        for (int jj = 0; jj < 2; ++jj) {
            gA[jj] = A + (size_t)(brow + rr[jj]) * K + ss[jj] * 16;
            gW[jj] = W + (size_t)(bcol + rr[jj]) * K + ss[jj] * 16;
        }

        int4v acc[MT][NT];
        const int4v izero = {0, 0, 0, 0};
#pragma unroll
        for (int mt = 0; mt < MT; ++mt)
#pragma unroll
            for (int nt = 0; nt < NT; ++nt) acc[mt][nt] = izero;

#pragma unroll
        for (int jj = 0; jj < 2; ++jj) load_lds16(gA[jj], lA + lq[jj]);
#pragma unroll
        for (int jj = 0; jj < 2; ++jj) load_lds16(gW[jj], lB + lq[jj]);

        for (int kt = 0; kt < K / 128; ++kt) {
            const int cur = kt & 1;
            if (kt + 1 < K / 128) {
#pragma unroll
                for (int jj = 0; jj < 2; ++jj)
                    load_lds16(gA[jj] + (kt + 1) * 128, lA + (cur ^ 1) * 16384 + lq[jj]);
#pragma unroll
                for (int jj = 0; jj < 2; ++jj)
                    load_lds16(gW[jj] + (kt + 1) * 128, lB + (cur ^ 1) * 16384 + lq[jj]);
                WAIT_VM(4);
            } else {
                WAIT_VM(0);
            }
            __builtin_amdgcn_s_barrier();

#pragma unroll
            for (int kk = 0; kk < 2; ++kk) {
                const int sw = ((kk * 4 + quad) ^ x7) * 16;
                int4v af[MT], bfr[NT];
#pragma unroll
                for (int mt = 0; mt < MT; ++mt)
                    af[mt] = *(const int4v*)(lA + cur * 16384 + (arow0 + mt * 16) * 128 + sw);
#pragma unroll
                for (int nt = 0; nt < NT; ++nt)
                    bfr[nt] = *(const int4v*)(lB + cur * 16384 + (brow0 + nt * 16) * 128 + sw);
#pragma unroll
                for (int mt = 0; mt < MT; ++mt)
#pragma unroll
                    for (int nt = 0; nt < NT; ++nt)
                        acc[mt][nt] = __builtin_amdgcn_mfma_i32_16x16x64_i8(
                            af[mt], bfr[nt], acc[mt][nt], 0, 0, 0);
            }
            __builtin_amdgcn_s_barrier();
        }

        const int m0 = brow + wr * 32 + quad * 4;
        const int n0 = bcol + wc * 64 + l16;
#pragma unroll
        for (int mt = 0; mt < MT; ++mt)
#pragma unroll
            for (int nt = 0; nt < NT; ++nt) {
                const int n = n0 + nt * 16;
                const float bb = bias[n];
                const float dqn = dq[n];
#pragma unroll
                for (int i = 0; i < 4; ++i) {
                    const int m = m0 + mt * 16 + i;
                    out[(size_t)m * N + n] =
                        __float2bfloat16(fast_tanh((float)acc[mt][nt][i] * dqn + bb));
                }
            }
    }
}

// L3: RK4-fused GEMM. K=1024, N=512. 128x64 tiles (MT=2, NT=2).
__device__ __forceinline__ void p3(const bf16* __restrict__ A, const bf16* __restrict__ W,
                                   const float* __restrict__ bias,
                                   bf16* kacc, const bf16* hb_src,
                                   const float* h_src, float* h_out,
                                   bf16* hb_out, bf16* x0_out,
                                   const float* __restrict__ temb,
                                   float alpha, float dt6, int mode,
                                   char* smem, int by, int bxp) {
    constexpr int K = 1024, MT = 2, NT = 2;
    bf16* lA = (bf16*)smem;                 // 2 bufs x 8192 elems (16 KB each)
    bf16* lB = (bf16*)(smem + 32768);       // 2 bufs x 4096 elems ( 8 KB each)

    const int tid  = threadIdx.x;
    const int lane = tid & 63, w = tid >> 6;
    const int wr = w >> 1, wc = w & 1;
    const int quad = lane >> 4, l16 = lane & 15;
    const int brow  = by * 128;
    const int arow0 = wr * 32 + l16;
    const int brow0 = wc * 32 + l16;
    const int x7 = l16 & 7;

    int rrA[2], ssA[2], lqA[2];
#pragma unroll
    for (int jj = 0; jj < 2; ++jj) {
        const int q = tid + jj * 512;
        rrA[jj] = q >> 3; ssA[jj] = (q & 7) ^ (rrA[jj] & 7); lqA[jj] = q * 8;
    }
    const int qB = tid;                 // 512 chunks: 64 rows x 8 chunks
    const int rB = qB >> 3, sB = (qB & 7) ^ (rB & 7);
    const int lqB = qB * 8;

    for (int tt = 0; tt < 2; ++tt) {
        const int bcol = (bxp * 2 + tt) * 64;
        const bf16* gA[2];
#pragma unroll
        for (int jj = 0; jj < 2; ++jj)
            gA[jj] = A + (size_t)(brow + rrA[jj]) * K + ssA[jj] * 8;
        const bf16* gW = W + (size_t)(bcol + rB) * K + sB * 8;

        floatx4 acc[MT][NT];
        const floatx4 zero = {0.f, 0.f, 0.f, 0.f};
#pragma unroll
        for (int mt = 0; mt < MT; ++mt)
#pragma unroll
            for (int nt = 0; nt < NT; ++nt) acc[mt][nt] = zero;

#pragma unroll
        for (int jj = 0; jj < 2; ++jj) load_lds16(gA[jj], lA + lqA[jj]);
        load_lds16(gW, lB + lqB);

        for (int kt = 0; kt < K / 64; ++kt) {
            const int cur = kt & 1;
            if (kt + 1 < K / 64) {
#pragma unroll
                for (int jj = 0; jj < 2; ++jj)
                    load_lds16(gA[jj] + (kt + 1) * 64, lA + (cur ^ 1) * 8192 + lqA[jj]);
                load_lds16(gW + (kt + 1) * 64, lB + (cur ^ 1) * 4096 + lqB);
                WAIT_VM(3);
            } else {
                WAIT_VM(0);
            }
            __builtin_amdgcn_s_barrier();

#pragma unroll
            for (int kk = 0; kk < 2; ++kk) {
                const int sw = ((kk * 4 + quad) ^ x7) * 8;
                short8 af[MT], bfr[NT];
#pragma unroll
                for (int mt = 0; mt < MT; ++mt)
                    af[mt] = *(const short8*)(lA + cur * 8192 + (arow0 + mt * 16) * 64 + sw);
#pragma unroll
                for (int nt = 0; nt < NT; ++nt)
                    bfr[nt] = *(const short8*)(lB + cur * 4096 + (brow0 + nt * 16) * 64 + sw);
#pragma unroll
                for (int mt = 0; mt < MT; ++mt)
#pragma unroll
                    for (int nt = 0; nt < NT; ++nt)
                        acc[mt][nt] = __builtin_amdgcn_mfma_f32_16x16x32_bf16(
                            af[mt], bfr[nt], acc[mt][nt], 0, 0, 0);
            }
            __builtin_amdgcn_s_barrier();
        }

        const int m0 = brow + wr * 32 + quad * 4;
        const int n0 = bcol + wc * 32 + l16;
#pragma unroll
        for (int mt = 0; mt < MT; ++mt)
#pragma unroll
            for (int nt = 0; nt < NT; ++nt) {
                const int n = n0 + nt * 16;
                const float bb = bias[n];
                const float te = temb[n];
#pragma unroll
                for (int i = 0; i < 4; ++i) {
                    const int m = m0 + mt * 16 + i;
                    const size_t idx = (size_t)m * 512 + n;
                    const float kv = acc[mt][nt][i] + bb;
                    if (mode == 0) {
                        kacc[idx] = __float2bfloat16(kv);
                        x0_out[idx] = __float2bfloat16(
                            __bfloat162float(hb_src[idx]) + alpha * kv + te);
                    } else if (mode == 1) {
                        kacc[idx] = __float2bfloat16(__bfloat162float(kacc[idx]) + 2.f * kv);
                        x0_out[idx] = __float2bfloat16(
                            __bfloat162float(hb_src[idx]) + alpha * kv + te);
                    } else {
                        const float hn = h_src[idx] + dt6 * (__bfloat162float(kacc[idx]) + kv);
                        h_out[idx] = hn;
                        hb_out[idx] = __float2bfloat16(hn);
                        if (x0_out) x0_out[idx] = __float2bfloat16(hn + te);
                    }
                }
            }
    }
}

__global__ void __launch_bounds__(512, 4)
ode_persist(const float* h_in, float* hbuf,
            const bf16* W1b, const float* b1,
            const int8_t* W2i, const float* dqv, const float* b2,
            const bf16* W3b, const float* b3,
            bf16* x0b, int8_t* x1i, bf16* x2b,
            bf16* kacc, bf16* hb, const float* temb, unsigned* bar) {
    __shared__ alignas(16) char smem[65536];
    const int b   = blockIdx.x;            // 256 blocks
    const int xcd = b & 7, j = b >> 3;     // j in 0..31
    const int by  = xcd + 8 * (j >> 2);    // 0..63 row-panels
    const int bxp = j & 3;                 // column-tile pair
    unsigned ep = 0;
    const float dt = 0.1f;

    for (int s = 0; s < 10; ++s) {
        const float* hs   = (s == 0) ? h_in : hbuf;
        const float* tmid = temb + (size_t)(2 * s + 1) * 512;
        const float* tend = temb + (size_t)(2 * s + 2) * 512;
        for (int e = 0; e < 4; ++e) {
            p1(x0b, W1b, b1, x1i, smem, by, bxp);
            grid_bar(bar, ++ep);
            p2(x1i, W2i, dqv, b2, x2b, smem, by, bxp);
            grid_bar(bar, ++ep);
            if (e == 0)
                p3(x2b, W3b, b3, kacc, hb, hs, nullptr, nullptr, x0b,
                   tmid, dt * 0.5f, 0.f, 0, smem, by, bxp);
            else if (e == 1)
                p3(x2b, W3b, b3, kacc, hb, hs, nullptr, nullptr, x0b,
                   tmid, dt * 0.5f, 0.f, 1, smem, by, bxp);
            else if (e == 2)
                p3(x2b, W3b, b3, kacc, hb, hs, nullptr, nullptr, x0b,
                   tend, dt, 0.f, 1, smem, by, bxp);
            else
                p3(x2b, W3b, b3, kacc, hb, hs, hbuf, hb,
                   (s == 9) ? nullptr : x0b, tend, 0.f, dt / 6.f, 2,
                   smem, by, bxp);
            if (s != 9 || e != 3) grid_bar(bar, ++ep);
        }
    }
}

// ===========================================================================
// Prep kernels (unchanged, verified).
// ===========================================================================

__global__ void f2b_kern(const float* __restrict__ src, bf16* __restrict__ dst, int n) {
    const int i = blockIdx.x * blockDim.x + threadIdx.x;
    if (i < n) dst[i] = __float2bfloat16(src[i]);
}

// Per-row i8 quantization of W2 (N=1024 rows, K=1024): row n scaled by
// 127/rowmax_n (clamped), dq[n] = rowmax_n/127^2 (includes x1's /127).
__global__ void quantW2_row(const float* __restrict__ W, int K,
                            int8_t* __restrict__ out, float* __restrict__ dq) {
    __shared__ float red[256];
    const int row = blockIdx.x, tid = threadIdx.x;
    const float* src = W + (size_t)row * K;
    float m = 0.f;
    for (int k = tid; k < K; k += 256) m = fmaxf(m, fabsf(src[k]));
    red[tid] = m;
    __syncthreads();
    for (int s = 128; s > 0; s >>= 1) {
        if (tid < s) red[tid] = fmaxf(red[tid], red[tid + s]);
        __syncthreads();
    }
    const float rmax = fmaxf(red[0], 1e-8f);
    const float sc = 127.f / rmax;
    int8_t* dst = out + (size_t)row * K;
    for (int k = tid; k < K; k += 256) {
        int v = __float2int_rn(src[k] * sc);
        v = v > 127 ? 127 : (v < -127 ? -127 : v);
        dst[k] = (int8_t)v;
    }
    if (tid == 0) dq[row] = rmax / (127.f * 127.f);
}

// temb[j][n] = (j*dt/2)*Wt[n] + bt[n], j = 0..20. Also zeroes the barrier.
__global__ void temb_kern(const float* __restrict__ Wt, const float* __restrict__ bt,
                          float* __restrict__ temb, float half_dt, int total,
                          unsigned* bar) {
    const int i = blockIdx.x * blockDim.x + threadIdx.x;
    if (i == 0) *bar = 0u;
    if (i < total) {
        const int j = i >> 9, n = i & 511;
        temb[i] = (j * half_dt) * Wt[n] + bt[n];
    }
}

__global__ void prep_kern(const float* __restrict__ h, const float* __restrict__ temb0,
                          bf16* __restrict__ x0, bf16* __restrict__ hb, int total) {
    const int i = blockIdx.x * blockDim.x + threadIdx.x;
    if (i < total) {
        const float hv = h[i];
        x0[i] = __float2bfloat16(hv + temb0[i & 511]);
        hb[i] = __float2bfloat16(hv);
    }
}

extern "C" void kernel_launch(void* const* d_in, const int* in_sizes, int n_in,
                              void* d_out, int out_size, void* d_ws, size_t ws_size,
                              hipStream_t stream) {
    const float* h_in = (const float*)d_in[0];
    const float* W1 = (const float*)d_in[1];
    const float* b1 = (const float*)d_in[2];
    const float* W2 = (const float*)d_in[3];
    const float* b2 = (const float*)d_in[4];
    const float* W3 = (const float*)d_in[5];
    const float* b3 = (const float*)d_in[6];
    const float* Wt = (const float*)d_in[7];
    const float* bt = (const float*)d_in[8];
    const int B = 8192, H = 512, H2 = 1024;
    const float dt = 0.1f;

    char* ws = (char*)d_ws;
    auto alloc = [&](size_t bytes) {
        char* p = ws;
        ws += (bytes + 255) & ~(size_t)255;
        return p;
    };
    bf16* W1b = (bf16*)alloc((size_t)H2 * H * 2);
    int8_t* W2i = (int8_t*)alloc((size_t)H2 * H2);      // i8, per-row scaled
    float* dqv  = (float*)alloc((size_t)H2 * 4);        // per-row dequant
    bf16* W3b = (bf16*)alloc((size_t)H * H2 * 2);
    bf16* x0b = (bf16*)alloc((size_t)B * H * 2);
    int8_t* x1i = (int8_t*)alloc((size_t)B * H2);       // i8 tanh outputs *127
    bf16* x2b = (bf16*)alloc((size_t)B * H2 * 2);
    bf16* kacc = (bf16*)alloc((size_t)B * H * 2);
    bf16* hb   = (bf16*)alloc((size_t)B * H * 2);
    float* temb = (float*)alloc((size_t)21 * H * 4);
    unsigned* bar = (unsigned*)alloc(256);              // grid-barrier counter
    float* hbuf = (float*)d_out;  // h lives in d_out (fp32)

    {
        int n = H2 * H;
        f2b_kern<<<(n + 255) / 256, 256, 0, stream>>>(W1, W1b, n);
        quantW2_row<<<H2, 256, 0, stream>>>(W2, H2, W2i, dqv);
        n = H * H2;
        f2b_kern<<<(n + 255) / 256, 256, 0, stream>>>(W3, W3b, n);
    }
    {
        const int total = 21 * H;
        temb_kern<<<(total + 255) / 256, 256, 0, stream>>>(Wt, bt, temb, dt * 0.5f,
                                                           total, bar);
    }
    {
        const int total = B * H;
        prep_kern<<<(total + 255) / 256, 256, 0, stream>>>(h_in, temb, x0b, hb, total);
    }

    // Single persistent kernel for all 40 ODE evals (plain launch).
    ode_persist<<<dim3(256), dim3(512), 0, stream>>>(
        h_in, hbuf, W1b, b1, W2i, dqv, b2, W3b, b3,
        x0b, x1i, x2b, kacc, hb, temb, bar);
}